// Round 20
// baseline (78.181 us; speedup 1.0000x reference)
//
#include <hip/hip_runtime.h>
#include <hip/hip_fp16.h>

// SimpleMHA2D: B=32, S=HW=1024, C=KV=1024, N=16, K=V=64, fp32.
//  K1: qkb B-fragments (fp16): qkb[kb][lane][j] = qk[c][n],
//      c = kb*32 + (lane>>4)*8 + j, n = lane&15.
//  K2 (fused, per 64-row chunk, 512 thr / 8 waves, 4 blocks/CU):
//      phase A = MFMA logits (4 row-tiles x 2 K-halves, R13 combine)
//      -> chunk softmax (2-pass, R12) -> phase C = MFMA wp = E^T X
//      (wave = 128 c, 8 tiles) -> wp fp16.  Deferred rescale in K3.
//      NO LDS buffer reuse anywhere (overlay banned per R4/R14).
//  K3: out[b][n][v] = (sum_ch fac*wp . vk)/(sum_ch fac*l_ch) + vb.

typedef _Float16 f16x8 __attribute__((ext_vector_type(8)));
typedef float f32x4 __attribute__((ext_vector_type(4)));

// ---------------- K1: fold query into k_kernel (emit B-fragment layout) ----------------
__global__ __launch_bounds__(256) void k_qk(const float* __restrict__ kk,
                                            const float* __restrict__ q,
                                            const float* __restrict__ kb,
                                            __half* __restrict__ qkb,
                                            float* __restrict__ qb) {
  const int gid = blockIdx.x * 256 + threadIdx.x;   // 16384 = 1024c * 16n
  const int c = gid >> 4, n = gid & 15;
  float a = 0.f;
#pragma unroll
  for (int k4 = 0; k4 < 64; k4 += 4) {
    const float4 kv = *(const float4*)(kk + (size_t)c * 1024 + n * 64 + k4);
    const float4 qv = *(const float4*)(q + n * 64 + k4);
    a += kv.x * qv.x + kv.y * qv.y + kv.z * qv.z + kv.w * qv.w;
  }
  // B-fragment position: kb=c>>5, lane=((c>>3)&3)*16+n, j=c&7
  const int kbi = c >> 5;
  const int l = (((c >> 3) & 3) << 4) | n;
  const int j = c & 7;
  qkb[kbi * 512 + l * 8 + j] = __float2half(a);
  if (blockIdx.x == 0 && threadIdx.x < 16) {
    float s = 0.f;
    for (int k = 0; k < 64; k++) s += kb[threadIdx.x * 64 + k] * q[threadIdx.x * 64 + k];
    qb[threadIdx.x] = s;
  }
}

// ---------------- K2: fused MFMA logits + chunk softmax + MFMA weighted sum ----------------
// 512 blocks (32 b x 16 chunks of 64 rows), 512 thr (8 waves).
// LDS: qkt 32 KB (read-only after staging) + et2 4.4 KB = 36.3 KB
//  -> 4 blocks/CU (145 KB LDS, 2048 thr) = 4 independent barrier groups.
__global__ __launch_bounds__(512, 8) void k_fused(const float* __restrict__ x,
                                                  const __half* __restrict__ qkb,
                                                  const float* __restrict__ qb,
                                                  float* __restrict__ mch,
                                                  float* __restrict__ lch,
                                                  __half* __restrict__ wph) {
  __shared__ __half qkt[16384];    // 32 KB B-fragments, never written after staging
  __shared__ float et2[64 * 17 + 4];
  const int tid = threadIdx.x;
  const int lane = tid & 63;
  const int wid = tid >> 6;          // 0..7
  const int blk = blockIdx.x;        // b*16 + ch
  const int srow0 = blk * 64;        // global row base

  // stage qkb -> qkt (identity copy, 2048 uint4)
#pragma unroll
  for (int it = 0; it < 4; ++it) {
    const int g = it * 512 + tid;
    ((uint4*)qkt)[g] = ((const uint4*)qkb)[g];
  }
  __syncthreads();

  // ---- Phase A: logits via MFMA; wave = (khalf<<2)|wtile (R13 scheme) ----
  {
    const int wtile = wid & 3;       // row tile 0..3 (16 rows each)
    const int khalf = wid >> 2;      // K half 0..1 (512 c each)
    const int r16 = lane & 15;       // A row within tile / D col (n)
    const int khi = lane >> 4;       // 0..3
    const float* xg = x + (size_t)(srow0 + wtile * 16 + r16) * 1024
                        + khalf * 512 + khi * 8;
    const __half* qbase = qkt + (khalf * 16) * 512 + lane * 8;

    f32x4 dacc = {0.f, 0.f, 0.f, 0.f};
    float4 pa0 = *(const float4*)(xg);
    float4 pa1 = *(const float4*)(xg + 4);
    float4 pb0, pb1;

#pragma unroll 1
    for (int kbs = 0; kbs < 16; kbs += 2) {
      pb0 = *(const float4*)(xg + (kbs + 1) * 32);
      pb1 = *(const float4*)(xg + (kbs + 1) * 32 + 4);
      {
        f16x8 af;
        af[0] = (_Float16)pa0.x; af[1] = (_Float16)pa0.y;
        af[2] = (_Float16)pa0.z; af[3] = (_Float16)pa0.w;
        af[4] = (_Float16)pa1.x; af[5] = (_Float16)pa1.y;
        af[6] = (_Float16)pa1.z; af[7] = (_Float16)pa1.w;
        const f16x8 bf = *(const f16x8*)(qbase + kbs * 512);
        dacc = __builtin_amdgcn_mfma_f32_16x16x32_f16(af, bf, dacc, 0, 0, 0);
      }
      if (kbs + 2 < 16) {
        pa0 = *(const float4*)(xg + (kbs + 2) * 32);
        pa1 = *(const float4*)(xg + (kbs + 2) * 32 + 4);
      }
      {
        f16x8 af;
        af[0] = (_Float16)pb0.x; af[1] = (_Float16)pb0.y;
        af[2] = (_Float16)pb0.z; af[3] = (_Float16)pb0.w;
        af[4] = (_Float16)pb1.x; af[5] = (_Float16)pb1.y;
        af[6] = (_Float16)pb1.z; af[7] = (_Float16)pb1.w;
        const f16x8 bf = *(const f16x8*)(qbase + (kbs + 1) * 512);
        dacc = __builtin_amdgcn_mfma_f32_16x16x32_f16(af, bf, dacc, 0, 0, 0);
      }
    }

    // D layout: row = khi*4+reg (s within tile), col = r16 (n)  [m89-verified]
    // combine: khalf0 writes (+qb), barrier, khalf1 adds (R13-validated).
    const float qbv = qb[r16];
    const int erow = wtile * 16 + khi * 4;
    if (khalf == 0) {
#pragma unroll
      for (int reg = 0; reg < 4; ++reg)
        et2[(erow + reg) * 17 + r16] = dacc[reg] + qbv;
    }
    __syncthreads();
    if (khalf == 1) {
#pragma unroll
      for (int reg = 0; reg < 4; ++reg)
        et2[(erow + reg) * 17 + r16] += dacc[reg];
    }
    __syncthreads();
  }

  // ---- Phase B: chunk softmax; wave handles n = wid, wid+8 (R12 scheme) ----
#pragma unroll
  for (int t = 0; t < 2; ++t) {
    const int nn = wid + t * 8;
    const float v = et2[lane * 17 + nn];
    float m = v;
#pragma unroll
    for (int d = 1; d < 64; d <<= 1) m = fmaxf(m, __shfl_xor(m, d));
    const float e = __expf(v - m);
    float s = e;
#pragma unroll
    for (int d = 1; d < 64; d <<= 1) s += __shfl_xor(s, d);
    if (lane == 0) {
      mch[blk * 16 + nn] = m;
      lch[blk * 16 + nn] = s;
    }
    et2[lane * 17 + nn] = e;   // in-place, same thread -> no race
  }
  __syncthreads();

  // ---- Phase C: wp[n][c] = E^T X via MFMA; wave <-> 128-c block, 8 tiles ----
  {
    const int r16 = lane & 15;
    const int sgp = lane >> 4;       // 0..3
    // A-fragments (E^T): afA covers s 0..31, afB covers s 32..63; shared by tiles
    f16x8 afA, afB;
#pragma unroll
    for (int j = 0; j < 8; ++j) {
      afA[j] = (_Float16)et2[(sgp * 8 + j) * 17 + r16];
      afB[j] = (_Float16)et2[(32 + sgp * 8 + j) * 17 + r16];
    }
    const float* xc = x + (size_t)srow0 * 1024 + wid * 128 + r16;
    __half* wpp = wph + (size_t)blk * 16384 + wid * 128 + r16;

    // depth-1 ping-pong on b-operands (named buffers)
    float b0a[8], b1a[8], b0b[8], b1b[8];
#pragma unroll
    for (int j = 0; j < 8; ++j) {
      b0a[j] = xc[(size_t)(sgp * 8 + j) * 1024];
      b1a[j] = xc[(size_t)(32 + sgp * 8 + j) * 1024];
    }
#pragma unroll
    for (int t = 0; t < 8; ++t) {
      if (t < 7) {
#pragma unroll
        for (int j = 0; j < 8; ++j) {
          b0b[j] = xc[(size_t)(sgp * 8 + j) * 1024 + (t + 1) * 16];
          b1b[j] = xc[(size_t)(32 + sgp * 8 + j) * 1024 + (t + 1) * 16];
        }
      }
      f16x8 bf0, bf1;
#pragma unroll
      for (int j = 0; j < 8; ++j) {
        bf0[j] = (_Float16)b0a[j];
        bf1[j] = (_Float16)b1a[j];
      }
      f32x4 dacc = {0.f, 0.f, 0.f, 0.f};
      dacc = __builtin_amdgcn_mfma_f32_16x16x32_f16(afA, bf0, dacc, 0, 0, 0);
      dacc = __builtin_amdgcn_mfma_f32_16x16x32_f16(afB, bf1, dacc, 0, 0, 0);
      // D: row = sgp*4+reg (n), col = r16 (c within tile)
#pragma unroll
      for (int reg = 0; reg < 4; ++reg)
        wpp[(size_t)(sgp * 4 + reg) * 1024 + t * 16] = __float2half(dacc[reg]);
#pragma unroll
      for (int j = 0; j < 8; ++j) { b0a[j] = b0b[j]; b1a[j] = b1b[j]; }
    }
  }
}

// ---------------- K3: out = (sum_ch fac*wp . vk)/lg + vb ----------------
__global__ __launch_bounds__(256) void k_out(const __half* __restrict__ wph,
                                             const float* __restrict__ vk,
                                             const float* __restrict__ vb,
                                             const float* __restrict__ mch,
                                             const float* __restrict__ lch,
                                             float* __restrict__ out) {
  const int bi = blockIdx.x;  // b*16+n, 512 blocks
  const int b = bi >> 4, n = bi & 15;
  const int tid = threadIdx.x;
  __shared__ float wrow[1024];
  __shared__ float red[4][64];

  float m16[16], l16[16];
#pragma unroll
  for (int ch = 0; ch < 16; ++ch) {
    m16[ch] = mch[(b * 16 + ch) * 16 + n];
    l16[ch] = lch[(b * 16 + ch) * 16 + n];
  }
  float mg = m16[0];
#pragma unroll
  for (int ch = 1; ch < 16; ++ch) mg = fmaxf(mg, m16[ch]);
  float fac[16], lg = 0.f;
#pragma unroll
  for (int ch = 0; ch < 16; ++ch) { fac[ch] = __expf(m16[ch] - mg); lg += fac[ch] * l16[ch]; }

  float4 a4 = {0.f, 0.f, 0.f, 0.f};
#pragma unroll
  for (int ch = 0; ch < 16; ch++) {
    const __half2* p = (const __half2*)(wph + ((size_t)(b * 16 + ch) * 16 + n) * 1024 + tid * 4);
    const float2 f01 = __half22float2(p[0]);
    const float2 f23 = __half22float2(p[1]);
    a4.x += fac[ch] * f01.x; a4.y += fac[ch] * f01.y;
    a4.z += fac[ch] * f23.x; a4.w += fac[ch] * f23.y;
  }
  *(float4*)&wrow[tid * 4] = a4;
  __syncthreads();

  const int v = tid & 63, cq = tid >> 6;
  float a = 0.f;
  const float* vkc = vk + n * 64 + v;
  for (int ci = 0; ci < 256; ci++) {
    const int c = cq * 256 + ci;
    a += wrow[c] * vkc[(size_t)c * 1024];
  }
  red[cq][v] = a;
  __syncthreads();
  if (tid < 64) {
    const float o = (red[0][tid] + red[1][tid] + red[2][tid] + red[3][tid]) / lg
                    + vb[n * 64 + tid];
    out[(size_t)b * 1024 + n * 64 + tid] = o;
  }
}

extern "C" void kernel_launch(void* const* d_in, const int* in_sizes, int n_in,
                              void* d_out, int out_size, void* d_ws, size_t ws_size,
                              hipStream_t stream) {
  const float* x  = (const float*)d_in[0];  // key_value [32,32,32,1024]
  const float* q  = (const float*)d_in[1];  // query [1,1,16,64]
  const float* kk = (const float*)d_in[2];  // k_kernel [1024,1024]
  const float* kb = (const float*)d_in[3];  // k_bias [1024]
  const float* vk = (const float*)d_in[4];  // v_kernel [1024,1024]
  const float* vb = (const float*)d_in[5];  // v_bias [1024]
  float* out = (float*)d_out;               // [32,16,64] fp32

  float*  f   = (float*)d_ws;
  __half* qkb = (__half*)f;            // 16384 halves = 32 KB (B-fragment layout)
  float*  qb  = f + 8192;              // 16
  float*  mch = f + 8208;              // 8192  [512 blk][16 n]
  float*  lch = f + 16400;             // 8192
  __half* wph = (__half*)(f + 24592);  // 8388608 halves = 16 MB

  hipLaunchKernelGGL(k_qk,    dim3(64),  dim3(256), 0, stream, kk, q, kb, qkb, qb);
  hipLaunchKernelGGL(k_fused, dim3(512), dim3(512), 0, stream, x, qkb, qb, mch, lch, wph);
  hipLaunchKernelGGL(k_out,   dim3(512), dim3(256), 0, stream, wph, vk, vb, mch, lch, out);
}

// Round 21
// 65.436 us; speedup vs baseline: 1.1948x; 1.1948x over previous
//
#include <hip/hip_runtime.h>
#include <hip/hip_fp16.h>

// SimpleMHA2D: B=32, S=HW=1024, C=KV=1024, N=16, K=V=64, fp32.
//  K1: qkb B-fragments (fp16): qkb[kb][lane][j] = qk[c][n],
//      c = kb*32 + (lane>>4)*8 + j, n = lane&15.
//  K2 (fused, per 64-row chunk, 1024 thr / 16 waves):  [VALIDATED R16 — frozen]
//      phase A = MFMA 16x16x32_f16 logits (4 row-tiles x 4 K-quarters)
//      -> chunk softmax -> phase C = MFMA wp = E^T X (wave = 64 c, 4 tiles)
//      -> wp fp16.  Deferred rescale in K3.  NO LDS buffer reuse anywhere.
//  K3: out[b][n][v] = (sum_ch fac*wp . vk)/(sum_ch fac*l_ch) + vb.

typedef _Float16 f16x8 __attribute__((ext_vector_type(8)));
typedef float f32x4 __attribute__((ext_vector_type(4)));

// ---------------- K1: fold query into k_kernel (emit B-fragment layout) ----------------
__global__ __launch_bounds__(256) void k_qk(const float* __restrict__ kk,
                                            const float* __restrict__ q,
                                            const float* __restrict__ kb,
                                            __half* __restrict__ qkb,
                                            float* __restrict__ qb) {
  const int gid = blockIdx.x * 256 + threadIdx.x;   // 16384 = 1024c * 16n
  const int c = gid >> 4, n = gid & 15;
  float a = 0.f;
#pragma unroll
  for (int k4 = 0; k4 < 64; k4 += 4) {
    const float4 kv = *(const float4*)(kk + (size_t)c * 1024 + n * 64 + k4);
    const float4 qv = *(const float4*)(q + n * 64 + k4);
    a += kv.x * qv.x + kv.y * qv.y + kv.z * qv.z + kv.w * qv.w;
  }
  // B-fragment position: kb=c>>5, lane=((c>>3)&3)*16+n, j=c&7
  const int kbi = c >> 5;
  const int l = (((c >> 3) & 3) << 4) | n;
  const int j = c & 7;
  qkb[kbi * 512 + l * 8 + j] = __float2half(a);
  if (blockIdx.x == 0 && threadIdx.x < 16) {
    float s = 0.f;
    for (int k = 0; k < 64; k++) s += kb[threadIdx.x * 64 + k] * q[threadIdx.x * 64 + k];
    qb[threadIdx.x] = s;
  }
}

// ---------------- K2: fused MFMA logits + chunk softmax + MFMA weighted sum ----------------
// 512 blocks (32 b x 16 chunks of 64 rows), 1024 thr (16 waves) -> 2 blk/CU.
// LDS: qkt 32 KB (read-only after staging) + et2/etB 2 x 4.4 KB ~= 41 KB.
__global__ __launch_bounds__(1024, 8) void k_fused(const float* __restrict__ x,
                                                   const __half* __restrict__ qkb,
                                                   const float* __restrict__ qb,
                                                   float* __restrict__ mch,
                                                   float* __restrict__ lch,
                                                   __half* __restrict__ wph) {
  __shared__ __half qkt[16384];    // 32 KB B-fragments, never written after staging
  __shared__ float et2[64 * 17 + 4];
  __shared__ float etB[64 * 17 + 4];
  const int tid = threadIdx.x;
  const int lane = tid & 63;
  const int wid = tid >> 6;          // 0..15
  const int blk = blockIdx.x;        // b*16 + ch
  const int srow0 = blk * 64;        // global row base

  // stage qkb -> qkt (identity copy, 2048 uint4)
#pragma unroll
  for (int it = 0; it < 2; ++it) {
    const int g = it * 1024 + tid;
    ((uint4*)qkt)[g] = ((const uint4*)qkb)[g];
  }
  __syncthreads();

  // ---- Phase A: logits via MFMA; wave = (kq<<2)|wtile ----
  {
    const int wtile = wid & 3;       // row tile 0..3 (16 rows each)
    const int kq = wid >> 2;         // K quarter 0..3 (256 c each)
    const int r16 = lane & 15;       // A row within tile / D col (n)
    const int khi = lane >> 4;       // 0..3
    const float* xg = x + (size_t)(srow0 + wtile * 16 + r16) * 1024
                        + kq * 256 + khi * 8;
    const __half* qbase = qkt + kq * 4096 + lane * 8;

    f32x4 dacc = {0.f, 0.f, 0.f, 0.f};
    float4 pa0 = *(const float4*)(xg);
    float4 pa1 = *(const float4*)(xg + 4);
    float4 pb0, pb1;

#pragma unroll 1
    for (int kbs = 0; kbs < 8; kbs += 2) {
      pb0 = *(const float4*)(xg + (kbs + 1) * 32);
      pb1 = *(const float4*)(xg + (kbs + 1) * 32 + 4);
      {
        f16x8 af;
        af[0] = (_Float16)pa0.x; af[1] = (_Float16)pa0.y;
        af[2] = (_Float16)pa0.z; af[3] = (_Float16)pa0.w;
        af[4] = (_Float16)pa1.x; af[5] = (_Float16)pa1.y;
        af[6] = (_Float16)pa1.z; af[7] = (_Float16)pa1.w;
        const f16x8 bf = *(const f16x8*)(qbase + kbs * 512);
        dacc = __builtin_amdgcn_mfma_f32_16x16x32_f16(af, bf, dacc, 0, 0, 0);
      }
      if (kbs + 2 < 8) {
        pa0 = *(const float4*)(xg + (kbs + 2) * 32);
        pa1 = *(const float4*)(xg + (kbs + 2) * 32 + 4);
      }
      {
        f16x8 af;
        af[0] = (_Float16)pb0.x; af[1] = (_Float16)pb0.y;
        af[2] = (_Float16)pb0.z; af[3] = (_Float16)pb0.w;
        af[4] = (_Float16)pb1.x; af[5] = (_Float16)pb1.y;
        af[6] = (_Float16)pb1.z; af[7] = (_Float16)pb1.w;
        const f16x8 bf = *(const f16x8*)(qbase + (kbs + 1) * 512);
        dacc = __builtin_amdgcn_mfma_f32_16x16x32_f16(af, bf, dacc, 0, 0, 0);
      }
    }

    // D layout: row = khi*4+reg (s within tile), col = r16 (n)  [m89-verified]
    // combine K-quarters: {kq0->et2, kq2->etB} write; {kq1,kq3} add.
    const int erow = wtile * 16 + khi * 4;
    if (kq == 0) {
#pragma unroll
      for (int reg = 0; reg < 4; ++reg) et2[(erow + reg) * 17 + r16] = dacc[reg];
    } else if (kq == 2) {
#pragma unroll
      for (int reg = 0; reg < 4; ++reg) etB[(erow + reg) * 17 + r16] = dacc[reg];
    }
    __syncthreads();
    if (kq == 1) {
#pragma unroll
      for (int reg = 0; reg < 4; ++reg) et2[(erow + reg) * 17 + r16] += dacc[reg];
    } else if (kq == 3) {
#pragma unroll
      for (int reg = 0; reg < 4; ++reg) etB[(erow + reg) * 17 + r16] += dacc[reg];
    }
    __syncthreads();
  }

  // ---- Phase B: chunk softmax; wave wid <-> n = wid, lane <-> row ----
  {
    const int nn = wid;
    const float v = et2[lane * 17 + nn] + etB[lane * 17 + nn] + qb[nn];
    float m = v;
#pragma unroll
    for (int d = 1; d < 64; d <<= 1) m = fmaxf(m, __shfl_xor(m, d));
    const float e = __expf(v - m);
    float s = e;
#pragma unroll
    for (int d = 1; d < 64; d <<= 1) s += __shfl_xor(s, d);
    if (lane == 0) {
      mch[blk * 16 + nn] = m;
      lch[blk * 16 + nn] = s;
    }
    et2[lane * 17 + nn] = e;   // in-place, same thread -> no race
  }
  __syncthreads();

  // ---- Phase C: wp[n][c] = E^T X via MFMA; wave <-> 64-c block, 4 tiles ----
  {
    const int r16 = lane & 15;
    const int sgp = lane >> 4;       // 0..3
    // A-fragments (E^T): afA covers s 0..31, afB covers s 32..63; shared by tiles
    f16x8 afA, afB;
#pragma unroll
    for (int j = 0; j < 8; ++j) {
      afA[j] = (_Float16)et2[(sgp * 8 + j) * 17 + r16];
      afB[j] = (_Float16)et2[(32 + sgp * 8 + j) * 17 + r16];
    }
    const float* xc = x + (size_t)srow0 * 1024 + wid * 64 + r16;
    __half* wpp = wph + (size_t)blk * 16384 + wid * 64 + r16;

    // depth-1 ping-pong on b-operands (named buffers)
    float b0a[8], b1a[8], b0b[8], b1b[8];
#pragma unroll
    for (int j = 0; j < 8; ++j) {
      b0a[j] = xc[(size_t)(sgp * 8 + j) * 1024];
      b1a[j] = xc[(size_t)(32 + sgp * 8 + j) * 1024];
    }
#pragma unroll
    for (int t = 0; t < 4; ++t) {
      if (t < 3) {
#pragma unroll
        for (int j = 0; j < 8; ++j) {
          b0b[j] = xc[(size_t)(sgp * 8 + j) * 1024 + (t + 1) * 16];
          b1b[j] = xc[(size_t)(32 + sgp * 8 + j) * 1024 + (t + 1) * 16];
        }
      }
      f16x8 bf0, bf1;
#pragma unroll
      for (int j = 0; j < 8; ++j) {
        bf0[j] = (_Float16)b0a[j];
        bf1[j] = (_Float16)b1a[j];
      }
      f32x4 dacc = {0.f, 0.f, 0.f, 0.f};
      dacc = __builtin_amdgcn_mfma_f32_16x16x32_f16(afA, bf0, dacc, 0, 0, 0);
      dacc = __builtin_amdgcn_mfma_f32_16x16x32_f16(afB, bf1, dacc, 0, 0, 0);
      // D: row = sgp*4+reg (n), col = r16 (c within tile)
#pragma unroll
      for (int reg = 0; reg < 4; ++reg)
        wpp[(size_t)(sgp * 4 + reg) * 1024 + t * 16] = __float2half(dacc[reg]);
#pragma unroll
      for (int j = 0; j < 8; ++j) { b0a[j] = b0b[j]; b1a[j] = b1b[j]; }
    }
  }
}

// ---------------- K3: out = (sum_ch fac*wp . vk)/lg + vb ----------------
__global__ __launch_bounds__(256) void k_out(const __half* __restrict__ wph,
                                             const float* __restrict__ vk,
                                             const float* __restrict__ vb,
                                             const float* __restrict__ mch,
                                             const float* __restrict__ lch,
                                             float* __restrict__ out) {
  const int bi = blockIdx.x;  // b*16+n, 512 blocks
  const int b = bi >> 4, n = bi & 15;
  const int tid = threadIdx.x;
  __shared__ float wrow[1024];
  __shared__ float red[4][64];

  float m16[16], l16[16];
#pragma unroll
  for (int ch = 0; ch < 16; ++ch) {
    m16[ch] = mch[(b * 16 + ch) * 16 + n];
    l16[ch] = lch[(b * 16 + ch) * 16 + n];
  }
  float mg = m16[0];
#pragma unroll
  for (int ch = 1; ch < 16; ++ch) mg = fmaxf(mg, m16[ch]);
  float fac[16], lg = 0.f;
#pragma unroll
  for (int ch = 0; ch < 16; ++ch) { fac[ch] = __expf(m16[ch] - mg); lg += fac[ch] * l16[ch]; }

  float4 a4 = {0.f, 0.f, 0.f, 0.f};
#pragma unroll
  for (int ch = 0; ch < 16; ch++) {
    const __half2* p = (const __half2*)(wph + ((size_t)(b * 16 + ch) * 16 + n) * 1024 + tid * 4);
    const float2 f01 = __half22float2(p[0]);
    const float2 f23 = __half22float2(p[1]);
    a4.x += fac[ch] * f01.x; a4.y += fac[ch] * f01.y;
    a4.z += fac[ch] * f23.x; a4.w += fac[ch] * f23.y;
  }
  *(float4*)&wrow[tid * 4] = a4;
  __syncthreads();

  const int v = tid & 63, cq = tid >> 6;
  float a = 0.f;
  const float* vkc = vk + n * 64 + v;
  for (int ci = 0; ci < 256; ci++) {
    const int c = cq * 256 + ci;
    a += wrow[c] * vkc[(size_t)c * 1024];
  }
  red[cq][v] = a;
  __syncthreads();
  if (tid < 64) {
    const float o = (red[0][tid] + red[1][tid] + red[2][tid] + red[3][tid]) / lg
                    + vb[n * 64 + tid];
    out[(size_t)b * 1024 + n * 64 + tid] = o;
  }
}

extern "C" void kernel_launch(void* const* d_in, const int* in_sizes, int n_in,
                              void* d_out, int out_size, void* d_ws, size_t ws_size,
                              hipStream_t stream) {
  const float* x  = (const float*)d_in[0];  // key_value [32,32,32,1024]
  const float* q  = (const float*)d_in[1];  // query [1,1,16,64]
  const float* kk = (const float*)d_in[2];  // k_kernel [1024,1024]
  const float* kb = (const float*)d_in[3];  // k_bias [1024]
  const float* vk = (const float*)d_in[4];  // v_kernel [1024,1024]
  const float* vb = (const float*)d_in[5];  // v_bias [1024]
  float* out = (float*)d_out;               // [32,16,64] fp32

  float*  f   = (float*)d_ws;
  __half* qkb = (__half*)f;            // 16384 halves = 32 KB (B-fragment layout)
  float*  qb  = f + 8192;              // 16
  float*  mch = f + 8208;              // 8192  [512 blk][16 n]
  float*  lch = f + 16400;             // 8192
  __half* wph = (__half*)(f + 24592);  // 8388608 halves = 16 MB

  hipLaunchKernelGGL(k_qk,    dim3(64),  dim3(256),  0, stream, kk, q, kb, qkb, qb);
  hipLaunchKernelGGL(k_fused, dim3(512), dim3(1024), 0, stream, x, qkb, qb, mch, lch, wph);
  hipLaunchKernelGGL(k_out,   dim3(512), dim3(256),  0, stream, wph, vk, vb, mch, lch, out);
}